// Round 4
// baseline (790.313 us; speedup 1.0000x reference)
//
#include <hip/hip_runtime.h>
#include <math.h>

#define N 16384
#define NWORDS 256       // N/64
#define FEAT 512
#define NUM_CATS 65
#define K 25
#define MAX_DETS 1000

typedef unsigned long long u64;
typedef unsigned int u32x4 __attribute__((ext_vector_type(4)));

// ---------------- ws layout (bytes) ----------------
// keys     : u64[N]            @ 0         (131072)
// rank     : u32[N]            @ 131072    (65536)
// sidx     : u32[N]            @ 196608    (65536)
// sbox     : float4[N]         @ 262144    (262144)
// sarea    : f32[N]            @ 524288    (65536)
// mask     : u64[N*NWORDS]     @ 589824    (33554432)
// idxArr   : i32[32]           @ 34144256  (128)   [31]=count
// keepOrig : u8[N]             @ 34144384  (16384)
// zeropad  : u64[256]          @ 34160768  (2048)  zeroed each launch by k_build
// total ~34.16 MB

// Sort key: descending by score, ties -> ascending original index.
// Block 0 also zeroes the zeropad region (ws is re-poisoned before each launch).
__global__ void k_build(const float* __restrict__ scores,
                        u64* __restrict__ keys,
                        unsigned int* __restrict__ rank,
                        u64* __restrict__ zeropad) {
    int i = blockIdx.x * 256 + threadIdx.x;
    keys[i] = ((u64)__float_as_uint(scores[i]) << 32) |
              (u64)(0xFFFFFFFFu - (unsigned)i);
    rank[i] = 0u;
    if (blockIdx.x == 0) zeropad[threadIdx.x] = 0ull;
}

// rank[i] = #{ j : key[j] > key[i] }  (keys distinct -> permutation)
__global__ void k_rank(const u64* __restrict__ keys,
                       unsigned int* __restrict__ rank) {
    __shared__ u64 lk[2048];
    int i = blockIdx.x * 256 + threadIdx.x;
    u64 my = keys[i];
    int j0 = blockIdx.y * 2048;
    for (int t = threadIdx.x; t < 2048; t += 256) lk[t] = keys[j0 + t];
    __syncthreads();
    unsigned int cnt = 0;
#pragma unroll 8
    for (int t = 0; t < 2048; ++t) cnt += (lk[t] > my) ? 1u : 0u;
    atomicAdd(&rank[i], cnt);
}

__global__ void k_scatter(const unsigned int* __restrict__ rank,
                          unsigned int* __restrict__ sidx) {
    int i = blockIdx.x * 256 + threadIdx.x;
    sidx[rank[i]] = (unsigned int)i;
}

// Gather boxes into sorted order; precompute areas (exact ref formula).
__global__ void k_gather(const unsigned int* __restrict__ sidx,
                         const float* __restrict__ det_boxes,
                         float4* __restrict__ sbox,
                         float* __restrict__ sarea) {
    int p = blockIdx.x * 256 + threadIdx.x;
    unsigned o = sidx[p];
    float4 b = ((const float4*)det_boxes)[o];   // [y1,x1,y2,x2]
    sbox[p] = b;
    sarea[p] = (b.w - b.y) * (b.z - b.x);       // (x2-x1)*(y2-y1)
}

// IoU>0.6 bit matrix, 256x256-box tiles per block (4 words/thread) to cut
// dispatch count 16x vs 64x64 tiles. Word (row, wi) is written iff it has
// any col > row (i.e. col0+63 >= row); fully-lower words stay garbage and
// are never read in a way that matters. Diagonal word of the last row in a
// word (col0+63 == row) IS written (as 0) because k_scan stages it.
__global__ void k_mask(const float4* __restrict__ sbox,
                       const float* __restrict__ sarea,
                       u64* __restrict__ mask) {
    int cg = blockIdx.x, rg = blockIdx.y;
    if (cg < rg) return;                    // strictly lower 256-tile
    __shared__ float4 cbox[256];
    __shared__ float carea[256];
    int tid = threadIdx.x;
    cbox[tid] = sbox[cg * 256 + tid];
    carea[tid] = sarea[cg * 256 + tid];
    __syncthreads();
    int row = rg * 256 + tid;
    float4 r = sbox[row];
    float ra = sarea[row];
    for (int cw = 0; cw < 4; ++cw) {
        int col0 = cg * 256 + cw * 64;
        if (col0 + 63 < row) continue;      // no col > row and k_scan never stages it
        u64 bits = 0ull;
        if (col0 > row) {
            // strictly upper word: every col > row, no per-col compare
            for (int j = 0; j < 64; ++j) {
                float4 cbx = cbox[cw * 64 + j];
                float iw = fminf(r.w, cbx.w) - fmaxf(r.y, cbx.y);
                iw = fmaxf(iw, 0.0f);
                float ih = fminf(r.z, cbx.z) - fmaxf(r.x, cbx.x);
                ih = fmaxf(ih, 0.0f);
                float inter = iw * ih;
                float iou = inter / (ra + carea[cw * 64 + j] - inter + 1e-12f);
                if (iou > 0.6f) bits |= (1ull << j);
            }
        } else {
            // diagonal word
            for (int j = 0; j < 64; ++j) {
                int col = col0 + j;
                if (col > row) {
                    float4 cbx = cbox[cw * 64 + j];
                    float iw = fminf(r.w, cbx.w) - fmaxf(r.y, cbx.y);
                    iw = fmaxf(iw, 0.0f);
                    float ih = fminf(r.z, cbx.z) - fmaxf(r.x, cbx.x);
                    ih = fmaxf(ih, 0.0f);
                    float inter = iw * ih;
                    float iou = inter / (ra + carea[cw * 64 + j] - inter + 1e-12f);
                    if (iou > 0.6f) bits |= (1ull << j);
                }
            }
        }
        mask[(size_t)row * NWORDS + cg * 4 + cw] = bits;
    }
}

// Single-wave greedy scan, 128-bit chunks. supp bitmask in registers
// (lane W>>2 owns word W in reg W&3). Phase A decides keeps for 128 boxes
// using per-lane diagonal fragments broadcast via shfl (registers only).
// Phase B ORs kept rows into supp via ONE inline-asm block per group of 8
// rows: 16 global_load_dwordx4 + a single s_waitcnt vmcnt(0), results as
// asm outputs so the compiler cannot consume them early or split the batch
// (round-3 failure: allocator folded ORs in, serializing to ~3 latencies
// per chunk at VGPR_Count=48).
__global__ void __launch_bounds__(64, 1)
k_scan(const u64* __restrict__ mask,
       const unsigned int* __restrict__ sidx,
       const u64* __restrict__ zeropad,
       unsigned char* __restrict__ keepOrig) {
    __shared__ u64 keepw_arr[NWORDS];
    int lane = threadIdx.x;                       // 64 threads = 1 wave
    u64 s0 = 0, s1 = 0, s2 = 0, s3 = 0;           // supp words lane*4+0..3
    int cnt = 0;                                  // uniform across lanes
    const char* zp = (const char*)zeropad + lane * 32;

    // stage chunk 0 diagonal fragments:
    //  dA,dB = words 0,1 of row lane; dH = word 1 of row 64+lane
    ulonglong2 d2 = *(const ulonglong2*)&mask[(size_t)lane * NWORDS];
    u64 dA = d2.x, dB = d2.y;
    u64 dH = mask[(size_t)(64 + lane) * NWORDS + 1];

    for (int c = 0; c < 128; ++c) {
        if (cnt >= MAX_DETS) {                    // nothing further kept/suppressed
            for (int cc = 2 * c + lane; cc < NWORDS; cc += 64) keepw_arr[cc] = 0ull;
            break;
        }
        // prefetch next chunk's diagonal fragments
        u64 nA = 0, nB = 0, nH = 0;
        if (c + 1 < 128) {
            ulonglong2 n2 = *(const ulonglong2*)
                &mask[(size_t)(128 * (c + 1) + lane) * NWORDS + 2 * (c + 1)];
            nA = n2.x; nB = n2.y;
            nH = mask[(size_t)(128 * (c + 1) + 64 + lane) * NWORDS + 2 * (c + 1) + 1];
        }

        // broadcast supp words 2c, 2c+1 from owner lane (c>>1), regs (c&1)*2+{0,1}
        u64 w0 = (c & 1) ? s2 : s0;
        u64 w1 = (c & 1) ? s3 : s1;
        w0 = __shfl(w0, c >> 1, 64);
        w1 = __shfl(w1, c >> 1, 64);
        u64 alive0 = ~w0, alive1 = ~w1;

        // ---- phase A: greedy keeps, registers only (uniform on all lanes) ----
        u64 keep0 = 0ull, keep1 = 0ull;
        while (cnt < MAX_DETS) {
            if (alive0) {
                int t = __ffsll((long long)alive0) - 1;
                u64 d0 = __shfl(dA, t, 64);       // word 2c of row base+t (bits>t)
                u64 d1 = __shfl(dB, t, 64);       // word 2c+1 of row base+t
                u64 bit = 1ull << t;
                keep0 |= bit; ++cnt;
                alive0 &= ~(d0 | bit);
                alive1 &= ~d1;
            } else if (alive1) {
                int t = __ffsll((long long)alive1) - 1;
                u64 d1 = __shfl(dH, t, 64);       // word 2c+1 of row base+64+t (bits>t)
                u64 bit = 1ull << t;
                keep1 |= bit; ++cnt;
                alive1 &= ~(d1 | bit);
            } else break;
        }
        if (lane == 0) {
            keepw_arr[2 * c] = keep0;
            keepw_arr[2 * c + 1] = keep1;
        }

        // ---- phase B: batched suppression OR, 8 rows per asm batch ----
        if (cnt < MAX_DETS && (keep0 | keep1)) {
            u64 k0 = keep0, k1 = keep1;
            size_t rbase = (size_t)(128 * c);
            while (k0 | k1) {
                const char *P0, *P1, *P2, *P3, *P4, *P5, *P6, *P7;
#define FILL(Pi)                                                              \
                {                                                             \
                    if (k0) {                                                 \
                        int t = __ffsll((long long)k0) - 1; k0 &= k0 - 1;     \
                        Pi = (const char*)mask +                              \
                             (((rbase + (size_t)t) << 8) + ((size_t)lane << 2)) * 8; \
                    } else if (k1) {                                          \
                        int t = __ffsll((long long)k1) - 1; k1 &= k1 - 1;     \
                        Pi = (const char*)mask +                              \
                             (((rbase + 64 + (size_t)t) << 8) + ((size_t)lane << 2)) * 8; \
                    } else Pi = zp;                                           \
                }
                FILL(P0) FILL(P1) FILL(P2) FILL(P3)
                FILL(P4) FILL(P5) FILL(P6) FILL(P7)
#undef FILL
                u32x4 Qa0, Qb0, Qa1, Qb1, Qa2, Qb2, Qa3, Qb3;
                u32x4 Qa4, Qb4, Qa5, Qb5, Qa6, Qb6, Qa7, Qb7;
                asm volatile(
                    "global_load_dwordx4 %0, %16, off\n\t"
                    "global_load_dwordx4 %1, %16, off offset:16\n\t"
                    "global_load_dwordx4 %2, %17, off\n\t"
                    "global_load_dwordx4 %3, %17, off offset:16\n\t"
                    "global_load_dwordx4 %4, %18, off\n\t"
                    "global_load_dwordx4 %5, %18, off offset:16\n\t"
                    "global_load_dwordx4 %6, %19, off\n\t"
                    "global_load_dwordx4 %7, %19, off offset:16\n\t"
                    "global_load_dwordx4 %8, %20, off\n\t"
                    "global_load_dwordx4 %9, %20, off offset:16\n\t"
                    "global_load_dwordx4 %10, %21, off\n\t"
                    "global_load_dwordx4 %11, %21, off offset:16\n\t"
                    "global_load_dwordx4 %12, %22, off\n\t"
                    "global_load_dwordx4 %13, %22, off offset:16\n\t"
                    "global_load_dwordx4 %14, %23, off\n\t"
                    "global_load_dwordx4 %15, %23, off offset:16\n\t"
                    "s_waitcnt vmcnt(0)"
                    : "=&v"(Qa0), "=&v"(Qb0), "=&v"(Qa1), "=&v"(Qb1),
                      "=&v"(Qa2), "=&v"(Qb2), "=&v"(Qa3), "=&v"(Qb3),
                      "=&v"(Qa4), "=&v"(Qb4), "=&v"(Qa5), "=&v"(Qb5),
                      "=&v"(Qa6), "=&v"(Qb6), "=&v"(Qa7), "=&v"(Qb7)
                    : "v"(P0), "v"(P1), "v"(P2), "v"(P3),
                      "v"(P4), "v"(P5), "v"(P6), "v"(P7)
                    : "memory");
#define U64LO(q) (((u64)(q).y << 32) | (u64)(q).x)
#define U64HI(q) (((u64)(q).w << 32) | (u64)(q).z)
                s0 |= U64LO(Qa0) | U64LO(Qa1) | U64LO(Qa2) | U64LO(Qa3) |
                      U64LO(Qa4) | U64LO(Qa5) | U64LO(Qa6) | U64LO(Qa7);
                s1 |= U64HI(Qa0) | U64HI(Qa1) | U64HI(Qa2) | U64HI(Qa3) |
                      U64HI(Qa4) | U64HI(Qa5) | U64HI(Qa6) | U64HI(Qa7);
                s2 |= U64LO(Qb0) | U64LO(Qb1) | U64LO(Qb2) | U64LO(Qb3) |
                      U64LO(Qb4) | U64LO(Qb5) | U64LO(Qb6) | U64LO(Qb7);
                s3 |= U64HI(Qb0) | U64HI(Qb1) | U64HI(Qb2) | U64HI(Qb3) |
                      U64HI(Qb4) | U64HI(Qb5) | U64HI(Qb6) | U64HI(Qb7);
#undef U64LO
#undef U64HI
            }
        }
        dA = nA; dB = nB; dH = nH;
    }

    // scatter keep bits back to original index order
    __syncthreads();
    for (int i = lane; i < N; i += 64) {
        unsigned char b = (unsigned char)((keepw_arr[i >> 6] >> (i & 63)) & 1ull);
        keepOrig[sidx[i]] = b;
    }
}

// valid = keep & ~all(roi_boxes==0) & (score>=0.9) & (rescaled area>220);
// collect first K valid in original-index order + total count.
__global__ void k_select(const unsigned char* __restrict__ keepOrig,
                         const float* __restrict__ roi_boxes,
                         const float* __restrict__ roi_scores,
                         const float* __restrict__ det_boxes,
                         const float* __restrict__ info,
                         int* __restrict__ idxArr) {
    __shared__ int wcnt[16];
    int tid = threadIdx.x;
    if (tid < K) idxArr[tid] = 0;
    __syncthreads();
    float sy = info[4], sx = info[5];
    int base = 0;
    for (int ch = 0; ch < 16; ++ch) {
        int i = ch * 1024 + tid;
        bool keep = keepOrig[i] != 0;
        float4 rb = ((const float4*)roi_boxes)[i];
        bool nz = !((rb.x == 0.0f) && (rb.y == 0.0f) && (rb.z == 0.0f) && (rb.w == 0.0f));
        bool sc = roi_scores[i] >= 0.9f;
        float4 db = ((const float4*)det_boxes)[i];
        float r0 = db.x / sy, r1 = db.y / sx, r2 = db.z / sy, r3 = db.w / sx;
        bool big = ((r2 - r0) * (r3 - r1)) > 220.0f;
        bool valid = keep && nz && sc && big;
        unsigned long long bal = __ballot(valid);
        int wv = tid >> 6, lane = tid & 63;
        if (lane == 0) wcnt[wv] = (int)__popcll(bal);
        __syncthreads();
        int pre = 0, tot = 0;
        for (int w = 0; w < 16; ++w) { int cc = wcnt[w]; tot += cc; if (w < wv) pre += cc; }
        int rk = base + pre + (int)__popcll(bal & ((1ull << lane) - 1ull));
        if (valid && rk < K) idxArr[rk] = i;
        base += tot;
        __syncthreads();
    }
    if (tid == 0) idxArr[31] = base;   // full valid count
}

// 25x65 classification, argmax/fg, stable descending sort, epilogue writes.
__global__ void k_classify(const float* __restrict__ vis,
                           const float* __restrict__ tf,
                           const float* __restrict__ det_boxes,
                           const float* __restrict__ info,
                           const int* __restrict__ idxArr,
                           float* __restrict__ out) {
    __shared__ float feat[K * FEAT];       // 51200 B
    __shared__ float sc[K * NUM_CATS];     // 6500 B
    __shared__ float keyL[K];
    __shared__ int fgL[K];
    __shared__ int ordL[K];
    int tid = threadIdx.x;
    int count = idxArr[31];
    int mincount = count < K ? count : K;

    for (int r = 0; r < K; ++r) {
        int o = idxArr[r];
        for (int e = tid; e < FEAT; e += 256)
            feat[r * FEAT + e] = vis[(size_t)o * FEAT + e];
    }
    __syncthreads();

    for (int p = tid; p < K * NUM_CATS; p += 256) {
        int r = p / NUM_CATS, c = p % NUM_CATS;
        const float* fr = &feat[r * FEAT];
        const float* tr = &tf[(size_t)c * FEAT];
        float s = 0.0f;
#pragma unroll 8
        for (int e = 0; e < FEAT; ++e) s += fr[e] * tr[e];
        sc[p] = s;
    }
    __syncthreads();

    if (tid < K) {
        float mv = sc[tid * NUM_CATS];
        int ma = 0;
        for (int c = 1; c < NUM_CATS; ++c) {
            float v = sc[tid * NUM_CATS + c];
            if (v > mv) { mv = v; ma = c; }     // first-max (jnp.argmax)
        }
        int fg = (tid < mincount) && (ma != 0);
        fgL[tid] = fg;
        keyL[tid] = fg ? mv : -INFINITY;
    }
    __syncthreads();

    if (tid == 0) {                 // stable selection sort, descending
        unsigned used = 0;
        for (int p = 0; p < K; ++p) {
            int bk = -1; float bv = 0.0f;
            for (int k2 = 0; k2 < K; ++k2) {
                if (used & (1u << k2)) continue;
                if (bk < 0 || keyL[k2] > bv) { bk = k2; bv = keyL[k2]; }
            }
            ordL[p] = bk;
            used |= (1u << bk);
        }
    }
    __syncthreads();

    float sy = info[4], sx = info[5];
    // scores: [0 .. 1599]
    for (int p = tid; p < K * (NUM_CATS - 1); p += 256) {
        int q = p >> 6, cc = p & 63;
        int src = ordL[q];
        out[p] = fgL[src] ? sc[src * NUM_CATS + cc + 1] : 0.0f;
    }
    // bboxes: [1600 .. 1699]  processed = [xmin, ymin, xmax, ymax]
    for (int p = tid; p < K * 4; p += 256) {
        int q = p >> 2, e = p & 3;
        int src = ordL[q];
        float v = 0.0f;
        if (fgL[src]) {
            int o = idxArr[src];
            float b0 = det_boxes[o * 4 + 0] / sy;   // ymin
            float b1 = det_boxes[o * 4 + 1] / sx;   // xmin
            float b2 = det_boxes[o * 4 + 2] / sy;   // ymax
            float b3 = det_boxes[o * 4 + 3] / sx;   // xmax
            v = (e == 0) ? b1 : (e == 1) ? b0 : (e == 2) ? b3 : b2;
        }
        out[1600 + p] = v;
    }
    // mask: [1700 .. 1724]
    if (tid < K) out[1700 + tid] = fgL[ordL[tid]] ? 1.0f : 0.0f;
}

extern "C" void kernel_launch(void* const* d_in, const int* in_sizes, int n_in,
                              void* d_out, int out_size, void* d_ws, size_t ws_size,
                              hipStream_t stream) {
    const float* roi_boxes  = (const float*)d_in[0];
    const float* roi_scores = (const float*)d_in[1];
    const float* det_boxes  = (const float*)d_in[2];
    // d_in[3] detection_masks: unused by reference
    const float* vis        = (const float*)d_in[4];
    const float* info       = (const float*)d_in[5];
    const float* tf         = (const float*)d_in[6];

    char* ws = (char*)d_ws;
    u64* keys                = (u64*)(ws + 0);
    unsigned int* rank       = (unsigned int*)(ws + 131072);
    unsigned int* sidx       = (unsigned int*)(ws + 196608);
    float4* sbox             = (float4*)(ws + 262144);
    float* sarea             = (float*)(ws + 524288);
    u64* mask                = (u64*)(ws + 589824);
    int* idxArr              = (int*)(ws + 34144256);
    unsigned char* keepOrig  = (unsigned char*)(ws + 34144384);
    u64* zeropad             = (u64*)(ws + 34160768);

    k_build<<<64, 256, 0, stream>>>(roi_scores, keys, rank, zeropad);
    k_rank<<<dim3(64, 8), 256, 0, stream>>>(keys, rank);
    k_scatter<<<64, 256, 0, stream>>>(rank, sidx);
    k_gather<<<64, 256, 0, stream>>>(sidx, det_boxes, sbox, sarea);
    k_mask<<<dim3(64, 64), 256, 0, stream>>>(sbox, sarea, mask);
    k_scan<<<1, 64, 0, stream>>>(mask, sidx, zeropad, keepOrig);
    k_select<<<1, 1024, 0, stream>>>(keepOrig, roi_boxes, roi_scores, det_boxes, info, idxArr);
    k_classify<<<1, 256, 0, stream>>>(vis, tf, det_boxes, info, idxArr, (float*)d_out);
}

// Round 5
// 702.192 us; speedup vs baseline: 1.1255x; 1.1255x over previous
//
#include <hip/hip_runtime.h>
#include <math.h>

#define N 16384
#define NWORDS 256       // N/64
#define FEAT 512
#define NUM_CATS 65
#define K 25
#define MAX_DETS 1000

typedef unsigned long long u64;
typedef unsigned int u32x4 __attribute__((ext_vector_type(4)));

// ---------------- ws layout (bytes) ----------------
// keys     : u64[N]            @ 0         (131072)  dead after k_rank;
//            tdiag u64[N] reuses this region (written by k_diag after k_gather)
// rank     : u32[N]            @ 131072    (65536)
// sidx     : u32[N]            @ 196608    (65536)
// sbox     : float4[N]         @ 262144    (262144)
// sarea    : f32[N]            @ 524288    (65536)
// mask     : u64[N*NWORDS]     @ 589824    (33554432)
// idxArr   : i32[32]           @ 34144256  (128)   [31]=count
// keepOrig : u8[N]             @ 34144384  (16384)
// zeropad  : u64[256]          @ 34160768  (2048)  zeroed each launch by k_build
// total ~34.16 MB

// Sort key: descending by score, ties -> ascending original index.
// Block 0 also zeroes the zeropad region (ws is re-poisoned each launch).
__global__ void k_build(const float* __restrict__ scores,
                        u64* __restrict__ keys,
                        unsigned int* __restrict__ rank,
                        u64* __restrict__ zeropad) {
    int i = blockIdx.x * 256 + threadIdx.x;
    keys[i] = ((u64)__float_as_uint(scores[i]) << 32) |
              (u64)(0xFFFFFFFFu - (unsigned)i);
    rank[i] = 0u;
    if (blockIdx.x == 0) zeropad[threadIdx.x] = 0ull;
}

// rank[i] = #{ j : key[j] > key[i] }  (keys distinct -> permutation)
__global__ void k_rank(const u64* __restrict__ keys,
                       unsigned int* __restrict__ rank) {
    __shared__ u64 lk[2048];
    int i = blockIdx.x * 256 + threadIdx.x;
    u64 my = keys[i];
    int j0 = blockIdx.y * 2048;
    for (int t = threadIdx.x; t < 2048; t += 256) lk[t] = keys[j0 + t];
    __syncthreads();
    unsigned int cnt = 0;
#pragma unroll 8
    for (int t = 0; t < 2048; ++t) cnt += (lk[t] > my) ? 1u : 0u;
    atomicAdd(&rank[i], cnt);
}

__global__ void k_scatter(const unsigned int* __restrict__ rank,
                          unsigned int* __restrict__ sidx) {
    int i = blockIdx.x * 256 + threadIdx.x;
    sidx[rank[i]] = (unsigned int)i;
}

// Gather boxes into sorted order; precompute areas (exact ref formula).
__global__ void k_gather(const unsigned int* __restrict__ sidx,
                         const float* __restrict__ det_boxes,
                         float4* __restrict__ sbox,
                         float* __restrict__ sarea) {
    int p = blockIdx.x * 256 + threadIdx.x;
    unsigned o = sidx[p];
    float4 b = ((const float4*)det_boxes)[o];   // [y1,x1,y2,x2]
    sbox[p] = b;
    sarea[p] = (b.w - b.y) * (b.z - b.x);       // (x2-x1)*(y2-y1)
}

// IoU>0.6 bit matrix, 256x256-box tiles per block (4 words/thread).
// Word (row, wi) written iff col0+63 >= row; fully-lower words stay
// garbage and are only ever OR'd into already-consumed supp words.
__global__ void k_mask(const float4* __restrict__ sbox,
                       const float* __restrict__ sarea,
                       u64* __restrict__ mask) {
    int cg = blockIdx.x, rg = blockIdx.y;
    if (cg < rg) return;                    // strictly lower 256-tile
    __shared__ float4 cbox[256];
    __shared__ float carea[256];
    int tid = threadIdx.x;
    cbox[tid] = sbox[cg * 256 + tid];
    carea[tid] = sarea[cg * 256 + tid];
    __syncthreads();
    int row = rg * 256 + tid;
    float4 r = sbox[row];
    float ra = sarea[row];
    for (int cw = 0; cw < 4; ++cw) {
        int col0 = cg * 256 + cw * 64;
        if (col0 + 63 < row) continue;
        u64 bits = 0ull;
        if (col0 > row) {
            for (int j = 0; j < 64; ++j) {
                float4 cbx = cbox[cw * 64 + j];
                float iw = fminf(r.w, cbx.w) - fmaxf(r.y, cbx.y);
                iw = fmaxf(iw, 0.0f);
                float ih = fminf(r.z, cbx.z) - fmaxf(r.x, cbx.x);
                ih = fmaxf(ih, 0.0f);
                float inter = iw * ih;
                float iou = inter / (ra + carea[cw * 64 + j] - inter + 1e-12f);
                if (iou > 0.6f) bits |= (1ull << j);
            }
        } else {
            for (int j = 0; j < 64; ++j) {
                int col = col0 + j;
                if (col > row) {
                    float4 cbx = cbox[cw * 64 + j];
                    float iw = fminf(r.w, cbx.w) - fmaxf(r.y, cbx.y);
                    iw = fmaxf(iw, 0.0f);
                    float ih = fminf(r.z, cbx.z) - fmaxf(r.x, cbx.x);
                    ih = fmaxf(ih, 0.0f);
                    float inter = iw * ih;
                    float iou = inter / (ra + carea[cw * 64 + j] - inter + 1e-12f);
                    if (iou > 0.6f) bits |= (1ull << j);
                }
            }
        }
        mask[(size_t)row * NWORDS + cg * 4 + cw] = bits;
    }
}

// Transposed diagonal blocks: tdiag[c*64+t] bit r (r<t) set iff box c*64+r
// suppresses box c*64+t. Expression DAG is syntactically identical to
// k_mask's (same fminf/fmaxf/div order) -> bitwise-identical decisions.
__global__ void k_diag(const float4* __restrict__ sbox,
                       const float* __restrict__ sarea,
                       u64* __restrict__ tdiag) {
    __shared__ float4 b[64];
    __shared__ float a[64];
    int c = blockIdx.x, t = threadIdx.x;
    b[t] = sbox[c * 64 + t];
    a[t] = sarea[c * 64 + t];
    __syncthreads();
    float4 mybox = b[t];        // column box (the suppressed one)
    float myarea = a[t];
    u64 bits = 0ull;
    for (int r = 0; r < 64; ++r) {
        if (r < t) {
            float4 rb = b[r];   // row box (the suppressor)
            float iw = fminf(rb.w, mybox.w) - fmaxf(rb.y, mybox.y);
            iw = fmaxf(iw, 0.0f);
            float ih = fminf(rb.z, mybox.z) - fmaxf(rb.x, mybox.x);
            ih = fmaxf(ih, 0.0f);
            float inter = iw * ih;
            float iou = inter / (a[r] + myarea - inter + 1e-12f);
            if (iou > 0.6f) bits |= (1ull << r);
        }
    }
    tdiag[c * 64 + t] = bits;
}

// Single-wave greedy scan, 64-bit chunks. supp bitmask in registers
// (lane W>>2 owns word W in reg W&3). Phase A: ballot-driven greedy with
// per-lane transposed diagonal columns — ZERO per-keep shfls (round-4
// failure: 2 dependent ds_bpermute per keep = ~250 cyc x 1000 keeps).
// Phase B: one inline-asm batch per 8 kept rows (16 global_load_dwordx4 +
// single s_waitcnt vmcnt(0), outputs as asm results so the allocator
// cannot fold/split the batch).
__global__ void __launch_bounds__(64, 1)
k_scan(const u64* __restrict__ mask,
       const u64* __restrict__ tdiag,
       const unsigned int* __restrict__ sidx,
       const u64* __restrict__ zeropad,
       unsigned char* __restrict__ keepOrig) {
    __shared__ u64 keepw_arr[NWORDS];
    int lane = threadIdx.x;                       // 64 threads = 1 wave
    u64 s0 = 0, s1 = 0, s2 = 0, s3 = 0;           // supp words lane*4+0..3
    int cnt = 0;                                  // uniform across lanes
    const char* zp = (const char*)zeropad + lane * 32;

    u64 colnext = tdiag[lane];                    // chunk 0 column prefetch

    for (int c = 0; c < NWORDS; ++c) {
        if (cnt >= MAX_DETS) {                    // nothing further kept/suppressed
            for (int cc = c + lane; cc < NWORDS; cc += 64) keepw_arr[cc] = 0ull;
            break;
        }
        u64 mycol = colnext;
        if (c + 1 < NWORDS)                       // prefetch next chunk's column
            colnext = tdiag[(c + 1) * 64 + lane];

        // broadcast supp word c from its owner lane/reg (one shfl per chunk)
        u64 sw;
        switch (c & 3) {
            case 0: sw = s0; break;
            case 1: sw = s1; break;
            case 2: sw = s2; break;
            default: sw = s3; break;
        }
        sw = __shfl(sw, c >> 2, 64);

        // ---- phase A: ballot greedy, no cross-lane data movement ----
        bool alive = !((sw >> lane) & 1ull);
        u64 keepw = 0ull;                         // uniform on all lanes
        while (cnt < MAX_DETS) {
            u64 bal = __ballot(alive);
            if (!bal) break;
            int k = __ffsll((long long)bal) - 1;  // lowest alive -> kept
            keepw |= 1ull << k;
            ++cnt;
            alive = alive && !((mycol >> k) & 1ull) && (lane != k);
        }
        if (lane == 0) keepw_arr[c] = keepw;

        // ---- phase B: batched suppression OR, 8 rows per asm batch ----
        if (cnt < MAX_DETS && keepw) {
            u64 kw = keepw;
            size_t rbase = (size_t)(c * 64);
            while (kw) {
                const char *P0, *P1, *P2, *P3, *P4, *P5, *P6, *P7;
#define FILL(Pi)                                                              \
                {                                                             \
                    if (kw) {                                                 \
                        int t = __ffsll((long long)kw) - 1; kw &= kw - 1;     \
                        Pi = (const char*)mask +                              \
                             (((rbase + (size_t)t) << 8) + ((size_t)lane << 2)) * 8; \
                    } else Pi = zp;                                           \
                }
                FILL(P0) FILL(P1) FILL(P2) FILL(P3)
                FILL(P4) FILL(P5) FILL(P6) FILL(P7)
#undef FILL
                u32x4 Qa0, Qb0, Qa1, Qb1, Qa2, Qb2, Qa3, Qb3;
                u32x4 Qa4, Qb4, Qa5, Qb5, Qa6, Qb6, Qa7, Qb7;
                asm volatile(
                    "global_load_dwordx4 %0, %16, off\n\t"
                    "global_load_dwordx4 %1, %16, off offset:16\n\t"
                    "global_load_dwordx4 %2, %17, off\n\t"
                    "global_load_dwordx4 %3, %17, off offset:16\n\t"
                    "global_load_dwordx4 %4, %18, off\n\t"
                    "global_load_dwordx4 %5, %18, off offset:16\n\t"
                    "global_load_dwordx4 %6, %19, off\n\t"
                    "global_load_dwordx4 %7, %19, off offset:16\n\t"
                    "global_load_dwordx4 %8, %20, off\n\t"
                    "global_load_dwordx4 %9, %20, off offset:16\n\t"
                    "global_load_dwordx4 %10, %21, off\n\t"
                    "global_load_dwordx4 %11, %21, off offset:16\n\t"
                    "global_load_dwordx4 %12, %22, off\n\t"
                    "global_load_dwordx4 %13, %22, off offset:16\n\t"
                    "global_load_dwordx4 %14, %23, off\n\t"
                    "global_load_dwordx4 %15, %23, off offset:16\n\t"
                    "s_waitcnt vmcnt(0)"
                    : "=&v"(Qa0), "=&v"(Qb0), "=&v"(Qa1), "=&v"(Qb1),
                      "=&v"(Qa2), "=&v"(Qb2), "=&v"(Qa3), "=&v"(Qb3),
                      "=&v"(Qa4), "=&v"(Qb4), "=&v"(Qa5), "=&v"(Qb5),
                      "=&v"(Qa6), "=&v"(Qb6), "=&v"(Qa7), "=&v"(Qb7)
                    : "v"(P0), "v"(P1), "v"(P2), "v"(P3),
                      "v"(P4), "v"(P5), "v"(P6), "v"(P7)
                    : "memory");
#define U64W0(q) (((u64)(q).y << 32) | (u64)(q).x)
#define U64W1(q) (((u64)(q).w << 32) | (u64)(q).z)
                s0 |= U64W0(Qa0) | U64W0(Qa1) | U64W0(Qa2) | U64W0(Qa3) |
                      U64W0(Qa4) | U64W0(Qa5) | U64W0(Qa6) | U64W0(Qa7);
                s1 |= U64W1(Qa0) | U64W1(Qa1) | U64W1(Qa2) | U64W1(Qa3) |
                      U64W1(Qa4) | U64W1(Qa5) | U64W1(Qa6) | U64W1(Qa7);
                s2 |= U64W0(Qb0) | U64W0(Qb1) | U64W0(Qb2) | U64W0(Qb3) |
                      U64W0(Qb4) | U64W0(Qb5) | U64W0(Qb6) | U64W0(Qb7);
                s3 |= U64W1(Qb0) | U64W1(Qb1) | U64W1(Qb2) | U64W1(Qb3) |
                      U64W1(Qb4) | U64W1(Qb5) | U64W1(Qb6) | U64W1(Qb7);
#undef U64W0
#undef U64W1
            }
        }
    }

    __syncthreads();
    // scatter keep bits back to original index order
    for (int i = lane; i < N; i += 64) {
        unsigned char b = (unsigned char)((keepw_arr[i >> 6] >> (i & 63)) & 1ull);
        keepOrig[sidx[i]] = b;
    }
}

// valid = keep & ~all(roi_boxes==0) & (score>=0.9) & (rescaled area>220);
// collect first K valid in original-index order + total count.
__global__ void k_select(const unsigned char* __restrict__ keepOrig,
                         const float* __restrict__ roi_boxes,
                         const float* __restrict__ roi_scores,
                         const float* __restrict__ det_boxes,
                         const float* __restrict__ info,
                         int* __restrict__ idxArr) {
    __shared__ int wcnt[16];
    int tid = threadIdx.x;
    if (tid < K) idxArr[tid] = 0;
    __syncthreads();
    float sy = info[4], sx = info[5];
    int base = 0;
    for (int ch = 0; ch < 16; ++ch) {
        int i = ch * 1024 + tid;
        bool keep = keepOrig[i] != 0;
        float4 rb = ((const float4*)roi_boxes)[i];
        bool nz = !((rb.x == 0.0f) && (rb.y == 0.0f) && (rb.z == 0.0f) && (rb.w == 0.0f));
        bool sc = roi_scores[i] >= 0.9f;
        float4 db = ((const float4*)det_boxes)[i];
        float r0 = db.x / sy, r1 = db.y / sx, r2 = db.z / sy, r3 = db.w / sx;
        bool big = ((r2 - r0) * (r3 - r1)) > 220.0f;
        bool valid = keep && nz && sc && big;
        unsigned long long bal = __ballot(valid);
        int wv = tid >> 6, lane = tid & 63;
        if (lane == 0) wcnt[wv] = (int)__popcll(bal);
        __syncthreads();
        int pre = 0, tot = 0;
        for (int w = 0; w < 16; ++w) { int cc = wcnt[w]; tot += cc; if (w < wv) pre += cc; }
        int rk = base + pre + (int)__popcll(bal & ((1ull << lane) - 1ull));
        if (valid && rk < K) idxArr[rk] = i;
        base += tot;
        __syncthreads();
    }
    if (tid == 0) idxArr[31] = base;   // full valid count
}

// 25x65 classification, argmax/fg, stable descending sort, epilogue writes.
__global__ void k_classify(const float* __restrict__ vis,
                           const float* __restrict__ tf,
                           const float* __restrict__ det_boxes,
                           const float* __restrict__ info,
                           const int* __restrict__ idxArr,
                           float* __restrict__ out) {
    __shared__ float feat[K * FEAT];       // 51200 B
    __shared__ float sc[K * NUM_CATS];     // 6500 B
    __shared__ float keyL[K];
    __shared__ int fgL[K];
    __shared__ int ordL[K];
    int tid = threadIdx.x;
    int count = idxArr[31];
    int mincount = count < K ? count : K;

    for (int r = 0; r < K; ++r) {
        int o = idxArr[r];
        for (int e = tid; e < FEAT; e += 256)
            feat[r * FEAT + e] = vis[(size_t)o * FEAT + e];
    }
    __syncthreads();

    for (int p = tid; p < K * NUM_CATS; p += 256) {
        int r = p / NUM_CATS, c = p % NUM_CATS;
        const float* fr = &feat[r * FEAT];
        const float* tr = &tf[(size_t)c * FEAT];
        float s = 0.0f;
#pragma unroll 8
        for (int e = 0; e < FEAT; ++e) s += fr[e] * tr[e];
        sc[p] = s;
    }
    __syncthreads();

    if (tid < K) {
        float mv = sc[tid * NUM_CATS];
        int ma = 0;
        for (int c = 1; c < NUM_CATS; ++c) {
            float v = sc[tid * NUM_CATS + c];
            if (v > mv) { mv = v; ma = c; }     // first-max (jnp.argmax)
        }
        int fg = (tid < mincount) && (ma != 0);
        fgL[tid] = fg;
        keyL[tid] = fg ? mv : -INFINITY;
    }
    __syncthreads();

    if (tid == 0) {                 // stable selection sort, descending
        unsigned used = 0;
        for (int p = 0; p < K; ++p) {
            int bk = -1; float bv = 0.0f;
            for (int k2 = 0; k2 < K; ++k2) {
                if (used & (1u << k2)) continue;
                if (bk < 0 || keyL[k2] > bv) { bk = k2; bv = keyL[k2]; }
            }
            ordL[p] = bk;
            used |= (1u << bk);
        }
    }
    __syncthreads();

    float sy = info[4], sx = info[5];
    // scores: [0 .. 1599]
    for (int p = tid; p < K * (NUM_CATS - 1); p += 256) {
        int q = p >> 6, cc = p & 63;
        int src = ordL[q];
        out[p] = fgL[src] ? sc[src * NUM_CATS + cc + 1] : 0.0f;
    }
    // bboxes: [1600 .. 1699]  processed = [xmin, ymin, xmax, ymax]
    for (int p = tid; p < K * 4; p += 256) {
        int q = p >> 2, e = p & 3;
        int src = ordL[q];
        float v = 0.0f;
        if (fgL[src]) {
            int o = idxArr[src];
            float b0 = det_boxes[o * 4 + 0] / sy;   // ymin
            float b1 = det_boxes[o * 4 + 1] / sx;   // xmin
            float b2 = det_boxes[o * 4 + 2] / sy;   // ymax
            float b3 = det_boxes[o * 4 + 3] / sx;   // xmax
            v = (e == 0) ? b1 : (e == 1) ? b0 : (e == 2) ? b3 : b2;
        }
        out[1600 + p] = v;
    }
    // mask: [1700 .. 1724]
    if (tid < K) out[1700 + tid] = fgL[ordL[tid]] ? 1.0f : 0.0f;
}

extern "C" void kernel_launch(void* const* d_in, const int* in_sizes, int n_in,
                              void* d_out, int out_size, void* d_ws, size_t ws_size,
                              hipStream_t stream) {
    const float* roi_boxes  = (const float*)d_in[0];
    const float* roi_scores = (const float*)d_in[1];
    const float* det_boxes  = (const float*)d_in[2];
    // d_in[3] detection_masks: unused by reference
    const float* vis        = (const float*)d_in[4];
    const float* info       = (const float*)d_in[5];
    const float* tf         = (const float*)d_in[6];

    char* ws = (char*)d_ws;
    u64* keys                = (u64*)(ws + 0);        // dead after k_rank
    u64* tdiag               = (u64*)(ws + 0);        // reuses keys' region
    unsigned int* rank       = (unsigned int*)(ws + 131072);
    unsigned int* sidx       = (unsigned int*)(ws + 196608);
    float4* sbox             = (float4*)(ws + 262144);
    float* sarea             = (float*)(ws + 524288);
    u64* mask                = (u64*)(ws + 589824);
    int* idxArr              = (int*)(ws + 34144256);
    unsigned char* keepOrig  = (unsigned char*)(ws + 34144384);
    u64* zeropad             = (u64*)(ws + 34160768);

    k_build<<<64, 256, 0, stream>>>(roi_scores, keys, rank, zeropad);
    k_rank<<<dim3(64, 8), 256, 0, stream>>>(keys, rank);
    k_scatter<<<64, 256, 0, stream>>>(rank, sidx);
    k_gather<<<64, 256, 0, stream>>>(sidx, det_boxes, sbox, sarea);
    k_mask<<<dim3(64, 64), 256, 0, stream>>>(sbox, sarea, mask);
    k_diag<<<256, 64, 0, stream>>>(sbox, sarea, tdiag);
    k_scan<<<1, 64, 0, stream>>>(mask, tdiag, sidx, zeropad, keepOrig);
    k_select<<<1, 1024, 0, stream>>>(keepOrig, roi_boxes, roi_scores, det_boxes, info, idxArr);
    k_classify<<<1, 256, 0, stream>>>(vis, tf, det_boxes, info, idxArr, (float*)d_out);
}